// Round 1
// baseline (463.323 us; speedup 1.0000x reference)
//
#include <hip/hip_runtime.h>

#define BD 8192
#define DD 512
#define KSPLIT 8
#define KRANGE (BD / KSPLIT)   // 1024
#define KB 16
#define TO 64
#define TI 64

__device__ __forceinline__ float polyev2(float c0, float c1, float c2, float w, float w2) {
    return c0 + c1 * w + c2 * w2;
}

// ---------------------------------------------------------------------------
// Kernel 1: column sums of x^{1,2,3}, s^{1,2,3}, y^{1,2,3}, s*y, s^2*y, s*y^2
// ws layout: 12 vectors of 512 floats:
// [0]=Sx [1]=Sx2 [2]=Sx3 [3]=Ss [4]=Ss2 [5]=Ss3 [6]=Sy [7]=Sy2 [8]=Sy3
// [9]=Ssy [10]=Ss2y [11]=Ssy2
// ---------------------------------------------------------------------------
__global__ __launch_bounds__(256) void colsum_kernel(
    const float* __restrict__ x, const float* __restrict__ s,
    const float* __restrict__ y, float* __restrict__ ws)
{
    int c  = blockIdx.x * 256 + threadIdx.x;   // column 0..511
    int r0 = blockIdx.y * 256;                 // row chunk start
    float xs1 = 0.f, xs2 = 0.f, xs3 = 0.f;
    float ss1 = 0.f, ss2 = 0.f, ss3 = 0.f;
    float ys1 = 0.f, ys2 = 0.f, ys3 = 0.f;
    float sy1 = 0.f, s2y = 0.f, sy2 = 0.f;
    for (int r = 0; r < 256; ++r) {
        size_t off = (size_t)(r0 + r) * DD + c;
        float xv = x[off], sv = s[off], yv = y[off];
        float xv2 = xv * xv; xs1 += xv; xs2 += xv2; xs3 += xv2 * xv;
        float sv2 = sv * sv; ss1 += sv; ss2 += sv2; ss3 += sv2 * sv;
        float yv2 = yv * yv; ys1 += yv; ys2 += yv2; ys3 += yv2 * yv;
        sy1 += sv * yv; s2y += sv2 * yv; sy2 += sv * yv2;
    }
    atomicAdd(&ws[0 * DD + c], xs1);  atomicAdd(&ws[1 * DD + c], xs2);  atomicAdd(&ws[2 * DD + c], xs3);
    atomicAdd(&ws[3 * DD + c], ss1);  atomicAdd(&ws[4 * DD + c], ss2);  atomicAdd(&ws[5 * DD + c], ss3);
    atomicAdd(&ws[6 * DD + c], ys1);  atomicAdd(&ws[7 * DD + c], ys2);  atomicAdd(&ws[8 * DD + c], ys3);
    atomicAdd(&ws[9 * DD + c], sy1);  atomicAdd(&ws[10 * DD + c], s2y); atomicAdd(&ws[11 * DD + c], sy2);
}

// ---------------------------------------------------------------------------
// Kernel 2: fused 7-GEMM (the ex>=1, es+ey>=1 triples) with epilogue.
// acc0 = s*x   -> poly p26 + p27*w          (1,1,0)
// acc1 = y*x   -> poly p23 + p24*w          (1,0,1)
// acc2 = s2*x  -> p29                       (1,2,0)
// acc3 = y2*x  -> p25                       (1,0,2)
// acc4 = sy*x  -> p28                       (1,1,1)
// acc5 = s*x2  -> p33                       (2,1,0)
// acc6 = y*x2  -> p32                       (2,0,1)
// atomicAdd invB * sum into out[o*512+i].
// ---------------------------------------------------------------------------
__global__ __launch_bounds__(256) void gemm7_kernel(
    const float* __restrict__ x, const float* __restrict__ s,
    const float* __restrict__ y, const float* __restrict__ w,
    const float* __restrict__ pw, float* __restrict__ out)
{
    __shared__ float lx[KB][TI];
    __shared__ float ls[KB][TO];
    __shared__ float ly[KB][TO];

    const int t  = threadIdx.x;
    const int tx = t & 15;          // i quad
    const int ty = t >> 4;          // o quad
    const int bid   = blockIdx.x;
    const int tileI = bid & 7;
    const int tileO = (bid >> 3) & 7;
    const int ks    = bid >> 6;
    const int iBase = tileI * TI;
    const int oBase = tileO * TO;
    const int kBase = ks * KRANGE;

    const int srow  = t >> 4;       // staging row 0..15
    const int scol  = (t & 15) * 4; // staging col (float4)

    float acc[7][4][4];
#pragma unroll
    for (int g = 0; g < 7; ++g)
#pragma unroll
        for (int r = 0; r < 4; ++r)
#pragma unroll
            for (int c = 0; c < 4; ++c) acc[g][r][c] = 0.f;

    for (int kt = 0; kt < KRANGE; kt += KB) {
        const size_t b = (size_t)(kBase + kt + srow);
        const float4 xv = *(const float4*)&x[b * DD + iBase + scol];
        const float4 sv = *(const float4*)&s[b * DD + oBase + scol];
        const float4 yv = *(const float4*)&y[b * DD + oBase + scol];
        __syncthreads();
        *(float4*)&lx[srow][scol] = xv;
        *(float4*)&ls[srow][scol] = sv;
        *(float4*)&ly[srow][scol] = yv;
        __syncthreads();
#pragma unroll
        for (int k = 0; k < KB; ++k) {
            const float4 xr = *(const float4*)&lx[k][tx * 4];
            const float4 sr = *(const float4*)&ls[k][ty * 4];
            const float4 yr = *(const float4*)&ly[k][ty * 4];
            float xa[4] = {xr.x, xr.y, xr.z, xr.w};
            float sa[4] = {sr.x, sr.y, sr.z, sr.w};
            float ya[4] = {yr.x, yr.y, yr.z, yr.w};
            float x2[4], s2[4], y2[4], syv[4];
#pragma unroll
            for (int c = 0; c < 4; ++c) x2[c] = xa[c] * xa[c];
#pragma unroll
            for (int r = 0; r < 4; ++r) {
                s2[r] = sa[r] * sa[r];
                y2[r] = ya[r] * ya[r];
                syv[r] = sa[r] * ya[r];
            }
#pragma unroll
            for (int r = 0; r < 4; ++r)
#pragma unroll
                for (int c = 0; c < 4; ++c) {
                    acc[0][r][c] += sa[r] * xa[c];
                    acc[1][r][c] += ya[r] * xa[c];
                    acc[2][r][c] += s2[r] * xa[c];
                    acc[3][r][c] += y2[r] * xa[c];
                    acc[4][r][c] += syv[r] * xa[c];
                    acc[5][r][c] += sa[r] * x2[c];
                    acc[6][r][c] += ya[r] * x2[c];
                }
        }
    }

    const float invB = 1.0f / (float)BD;
    const float p23 = pw[23], p24 = pw[24], p25 = pw[25], p26 = pw[26];
    const float p27 = pw[27], p28 = pw[28], p29 = pw[29], p32 = pw[32], p33 = pw[33];
#pragma unroll
    for (int r = 0; r < 4; ++r) {
        const int o = oBase + ty * 4 + r;
#pragma unroll
        for (int c = 0; c < 4; ++c) {
            const int i = iBase + tx * 4 + c;
            const float wv = w[o * DD + i];
            float contrib = acc[0][r][c] * (p26 + p27 * wv)
                          + acc[1][r][c] * (p23 + p24 * wv)
                          + acc[2][r][c] * p29
                          + acc[3][r][c] * p25
                          + acc[4][r][c] * p28
                          + acc[5][r][c] * p33
                          + acc[6][r][c] * p32;
            atomicAdd(&out[o * DD + i], invB * contrib);
        }
    }
}

// ---------------------------------------------------------------------------
// Kernel 3: rank-1 (ex=0 or es=ey=0) and constant terms added elementwise.
// ---------------------------------------------------------------------------
__global__ __launch_bounds__(256) void rank1_kernel(
    const float* __restrict__ w, const float* __restrict__ pw,
    const float* __restrict__ ws, float* __restrict__ out)
{
    const int idx = blockIdx.x * 256 + threadIdx.x;   // 0..262143
    const int o = idx >> 9;
    const int i = idx & 511;
    const float wv = w[idx];
    const float w2 = wv * wv, w3 = w2 * wv;
    const float invB = 1.0f / (float)BD;

    float acc = (float)BD * (pw[0] + pw[1] * wv + pw[2] * w2 + pw[3] * w3);
    // i-vectors (es=ey=0, ex>=1)
    acc += ws[0 * DD + i] * polyev2(pw[20], pw[21], pw[22], wv, w2);  // x
    acc += ws[1 * DD + i] * (pw[30] + pw[31] * wv);                  // x^2
    acc += ws[2 * DD + i] * pw[34];                                  // x^3
    // o-vectors (ex=0)
    acc += ws[6 * DD + o]  * polyev2(pw[4],  pw[5],  pw[6],  wv, w2); // y
    acc += ws[7 * DD + o]  * (pw[7] + pw[8] * wv);                    // y^2
    acc += ws[8 * DD + o]  * pw[9];                                   // y^3
    acc += ws[3 * DD + o]  * polyev2(pw[10], pw[11], pw[12], wv, w2); // s
    acc += ws[9 * DD + o]  * (pw[13] + pw[14] * wv);                  // s*y
    acc += ws[11 * DD + o] * pw[15];                                  // s*y^2
    acc += ws[4 * DD + o]  * (pw[16] + pw[17] * wv);                  // s^2
    acc += ws[10 * DD + o] * pw[18];                                  // s^2*y
    acc += ws[5 * DD + o]  * pw[19];                                  // s^3
    out[idx] += invB * acc;
}

// ---------------------------------------------------------------------------
// Kernel 4: delta_b
// ---------------------------------------------------------------------------
__global__ __launch_bounds__(256) void deltab_kernel(
    const float* __restrict__ bvec, const float* __restrict__ pb,
    const float* __restrict__ ws, float* __restrict__ out)
{
    const int o = blockIdx.x * 256 + threadIdx.x;
    if (o < DD) {
        const float bv = bvec[o];
        const float b2 = bv * bv, b3 = b2 * bv;
        const float invB = 1.0f / (float)BD;
        float acc = (float)BD * (pb[0] + pb[1] * bv + pb[2] * b2 + pb[3] * b3);
        acc += ws[6 * DD + o] * (pb[4] + pb[5] * bv + pb[6] * b2);
        acc += ws[7 * DD + o] * (pb[7] + pb[8] * bv);
        acc += ws[8 * DD + o] * pb[9];
        out[DD * DD + o] = invB * acc;
    }
}

extern "C" void kernel_launch(void* const* d_in, const int* in_sizes, int n_in,
                              void* d_out, int out_size, void* d_ws, size_t ws_size,
                              hipStream_t stream) {
    const float* x  = (const float*)d_in[0];
    const float* s  = (const float*)d_in[1];
    const float* y  = (const float*)d_in[2];
    const float* w  = (const float*)d_in[3];
    const float* b  = (const float*)d_in[4];
    const float* pw = (const float*)d_in[5];
    const float* pb = (const float*)d_in[6];
    float* out = (float*)d_out;
    float* ws  = (float*)d_ws;

    // zero the colsum accumulators and the delta_w output (atomics add into it)
    hipMemsetAsync(ws, 0, 12 * DD * sizeof(float), stream);
    hipMemsetAsync(out, 0, (size_t)(DD * DD + DD) * sizeof(float), stream);

    colsum_kernel<<<dim3(2, 32), 256, 0, stream>>>(x, s, y, ws);
    gemm7_kernel<<<dim3(512), 256, 0, stream>>>(x, s, y, w, pw, out);
    rank1_kernel<<<dim3((DD * DD) / 256), 256, 0, stream>>>(w, pw, ws, out);
    deltab_kernel<<<dim3(2), 256, 0, stream>>>(b, pb, ws, out);
}

// Round 2
// 179.848 us; speedup vs baseline: 2.5762x; 2.5762x over previous
//
#include <hip/hip_runtime.h>

#define BD 8192
#define DD 512
#define PLANE (BD * DD)          // elems per bf16 plane (4.19M)
#define NPLANES 5                // 0:A1 1:A2 2:A3 3:x 4:x^2

typedef __attribute__((ext_vector_type(4))) float f32x4;
typedef __attribute__((ext_vector_type(8))) short short8;

__device__ __forceinline__ float polyev2(float c0, float c1, float c2, float w, float w2) {
    return c0 + c1 * w + c2 * w2;
}

// float -> bf16 bits, round-to-nearest-even
__device__ __forceinline__ unsigned short f2b(float v) {
    unsigned u = __builtin_bit_cast(unsigned, v);
    u += 0x7FFFu + ((u >> 16) & 1u);
    return (unsigned short)(u >> 16);
}

__device__ __forceinline__ void gload_lds16(const unsigned short* g, unsigned short* l) {
    __builtin_amdgcn_global_load_lds((__attribute__((address_space(1))) const void*)g,
                                     (__attribute__((address_space(3))) void*)l, 16, 0, 0);
}

// ---------------------------------------------------------------------------
// prep: build bf16 planes A1,A2,A3,x,x2 in K-tiled layout plane[bt][col][32kk]
// and fold in the 12 column-sums (atomicAdd into cs).
// grid (8, 64), block 256: thread -> col o = bx*64 + (t&63), bt = by*4 + (t>>6)
// ---------------------------------------------------------------------------
__global__ __launch_bounds__(256) void prep_kernel(
    const float* __restrict__ x, const float* __restrict__ s,
    const float* __restrict__ y, const float* __restrict__ pw,
    unsigned short* __restrict__ pl, float* __restrict__ cs)
{
    const int t  = threadIdx.x;
    const int o  = blockIdx.x * 64 + (t & 63);
    const int bt = blockIdx.y * 4 + (t >> 6);
    const int b0 = bt * 32;
    const float p23 = pw[23], p24 = pw[24], p25 = pw[25], p26 = pw[26], p27 = pw[27];
    const float p28 = pw[28], p29 = pw[29], p32 = pw[32], p33 = pw[33];

    float xs1 = 0.f, xs2 = 0.f, xs3 = 0.f;
    float ss1 = 0.f, ss2 = 0.f, ss3 = 0.f;
    float ys1 = 0.f, ys2 = 0.f, ys3 = 0.f;
    float sy1 = 0.f, s2y = 0.f, sy2 = 0.f;

    unsigned pk[NPLANES][16];   // 32 bf16 per plane packed as 16 u32

#pragma unroll
    for (int j = 0; j < 32; ++j) {
        const size_t off = (size_t)(b0 + j) * DD + o;
        const float xv = x[off], sv = s[off], yv = y[off];
        const float xq = xv * xv, sq = sv * sv, yq = yv * yv, syv = sv * yv;
        xs1 += xv;  xs2 += xq;      xs3 += xq * xv;
        ss1 += sv;  ss2 += sq;      ss3 += sq * sv;
        ys1 += yv;  ys2 += yq;      ys3 += yq * yv;
        sy1 += syv; s2y += sq * yv; sy2 += sv * yq;

        unsigned short tmp[NPLANES];
        tmp[0] = f2b(p26 * sv + p23 * yv + p29 * sq + p25 * yq + p28 * syv);
        tmp[1] = f2b(p33 * sv + p32 * yv);
        tmp[2] = f2b(p27 * sv + p24 * yv);
        tmp[3] = f2b(xv);
        tmp[4] = f2b(xq);
        if ((j & 1) == 0) {
#pragma unroll
            for (int p = 0; p < NPLANES; ++p) pk[p][j >> 1] = (unsigned)tmp[p];
        } else {
#pragma unroll
            for (int p = 0; p < NPLANES; ++p) pk[p][j >> 1] |= (unsigned)tmp[p] << 16;
        }
    }

    const size_t wbase = ((size_t)bt * DD + o) * 32;   // elem offset, 64B aligned
#pragma unroll
    for (int p = 0; p < NPLANES; ++p) {
        uint4* dst = (uint4*)(pl + (size_t)p * PLANE + wbase);
#pragma unroll
        for (int c = 0; c < 4; ++c) {
            uint4 u;
            u.x = pk[p][c * 4 + 0]; u.y = pk[p][c * 4 + 1];
            u.z = pk[p][c * 4 + 2]; u.w = pk[p][c * 4 + 3];
            dst[c] = u;
        }
    }

    atomicAdd(&cs[0 * DD + o], xs1);  atomicAdd(&cs[1 * DD + o], xs2);  atomicAdd(&cs[2 * DD + o], xs3);
    atomicAdd(&cs[3 * DD + o], ss1);  atomicAdd(&cs[4 * DD + o], ss2);  atomicAdd(&cs[5 * DD + o], ss3);
    atomicAdd(&cs[6 * DD + o], ys1);  atomicAdd(&cs[7 * DD + o], ys2);  atomicAdd(&cs[8 * DD + o], ys3);
    atomicAdd(&cs[9 * DD + o], sy1);  atomicAdd(&cs[10 * DD + o], s2y); atomicAdd(&cs[11 * DD + o], sy2);
}

// ---------------------------------------------------------------------------
// gemm3: D_g = A_gᵀ @ B_g via bf16 MFMA 16x16x32. grid (16 tiles, KSPLIT=16, 3).
// g=0: A1@x (+1), g=1: A2@x2 (+1), g=2: A3@x (coef w). atomicAdd invB*val.
// Block 256 = 4 waves; 128x128 tile; wave quadrant 64x64 = 4x4 MFMA positions.
// ---------------------------------------------------------------------------
__global__ __launch_bounds__(256) void gemm3_kernel(
    const unsigned short* __restrict__ pl, const float* __restrict__ w,
    float* __restrict__ out)
{
    __shared__ unsigned short ldsA[128 * 32];
    __shared__ unsigned short ldsB[128 * 32];

    const int t    = threadIdx.x;
    const int lane = t & 63;
    const int wid  = t >> 6;
    const int g     = blockIdx.z;
    const int tileI = blockIdx.x & 3;
    const int tileO = blockIdx.x >> 2;
    const int kt0   = blockIdx.y * 16;      // 16 k-tiles of 32 per block

    const int aplane = (g == 0) ? 0 : (g == 1) ? 1 : 2;
    const int bplane = (g == 1) ? 4 : 3;
    const unsigned short* Ap = pl + (size_t)aplane * PLANE;
    const unsigned short* Bp = pl + (size_t)bplane * PLANE;

    const int wo = (wid >> 1) * 64;
    const int wi = (wid & 1) * 64;
    const int l15 = lane & 15;
    const int kchunk = (lane >> 4) * 8;

    f32x4 acc[4][4];
#pragma unroll
    for (int m = 0; m < 4; ++m)
#pragma unroll
        for (int n = 0; n < 4; ++n) acc[m][n] = (f32x4)0.f;

    unsigned short* ldsAw = ldsA + wid * 512;
    unsigned short* ldsBw = ldsB + wid * 512;
    const size_t tg = (size_t)t * 8;

    for (int kt = 0; kt < 16; ++kt) {
        const size_t abase = ((size_t)(kt0 + kt) * DD + tileO * 128) * 32;
        const size_t bbase = ((size_t)(kt0 + kt) * DD + tileI * 128) * 32;
        __syncthreads();
        gload_lds16(Ap + abase + tg,        ldsAw);
        gload_lds16(Ap + abase + 2048 + tg, ldsAw + 2048);
        gload_lds16(Bp + bbase + tg,        ldsBw);
        gload_lds16(Bp + bbase + 2048 + tg, ldsBw + 2048);
        __syncthreads();

        short8 af[4], bf[4];
#pragma unroll
        for (int m = 0; m < 4; ++m)
            af[m] = *(const short8*)&ldsA[(wo + m * 16 + l15) * 32 + kchunk];
#pragma unroll
        for (int n = 0; n < 4; ++n)
            bf[n] = *(const short8*)&ldsB[(wi + n * 16 + l15) * 32 + kchunk];
#pragma unroll
        for (int m = 0; m < 4; ++m)
#pragma unroll
            for (int n = 0; n < 4; ++n)
                acc[m][n] = __builtin_amdgcn_mfma_f32_16x16x32_bf16(af[m], bf[n], acc[m][n], 0, 0, 0);
    }

    const float invB = 1.0f / (float)BD;
    const int l4 = lane >> 4;
#pragma unroll
    for (int m = 0; m < 4; ++m) {
#pragma unroll
        for (int n = 0; n < 4; ++n) {
#pragma unroll
            for (int r = 0; r < 4; ++r) {
                const int o = tileO * 128 + wo + m * 16 + l4 * 4 + r;
                const int i = tileI * 128 + wi + n * 16 + l15;
                float v = acc[m][n][r] * invB;
                if (g == 2) v *= w[o * DD + i];
                atomicAdd(&out[o * DD + i], v);
            }
        }
    }
}

// ---------------------------------------------------------------------------
// rank1 + constant terms (elementwise over w), added after gemm3 (stream order)
// ---------------------------------------------------------------------------
__global__ __launch_bounds__(256) void rank1_kernel(
    const float* __restrict__ w, const float* __restrict__ pw,
    const float* __restrict__ cs, float* __restrict__ out)
{
    const int idx = blockIdx.x * 256 + threadIdx.x;   // 0..262143
    const int o = idx >> 9;
    const int i = idx & 511;
    const float wv = w[idx];
    const float w2 = wv * wv, w3 = w2 * wv;
    const float invB = 1.0f / (float)BD;

    float acc = (float)BD * (pw[0] + pw[1] * wv + pw[2] * w2 + pw[3] * w3);
    acc += cs[0 * DD + i] * polyev2(pw[20], pw[21], pw[22], wv, w2);  // x
    acc += cs[1 * DD + i] * (pw[30] + pw[31] * wv);                   // x^2
    acc += cs[2 * DD + i] * pw[34];                                   // x^3
    acc += cs[6 * DD + o]  * polyev2(pw[4],  pw[5],  pw[6],  wv, w2); // y
    acc += cs[7 * DD + o]  * (pw[7] + pw[8] * wv);                    // y^2
    acc += cs[8 * DD + o]  * pw[9];                                   // y^3
    acc += cs[3 * DD + o]  * polyev2(pw[10], pw[11], pw[12], wv, w2); // s
    acc += cs[9 * DD + o]  * (pw[13] + pw[14] * wv);                  // s*y
    acc += cs[11 * DD + o] * pw[15];                                  // s*y^2
    acc += cs[4 * DD + o]  * (pw[16] + pw[17] * wv);                  // s^2
    acc += cs[10 * DD + o] * pw[18];                                  // s^2*y
    acc += cs[5 * DD + o]  * pw[19];                                  // s^3
    out[idx] += invB * acc;
}

__global__ __launch_bounds__(256) void deltab_kernel(
    const float* __restrict__ bvec, const float* __restrict__ pb,
    const float* __restrict__ cs, float* __restrict__ out)
{
    const int o = blockIdx.x * 256 + threadIdx.x;
    if (o < DD) {
        const float bv = bvec[o];
        const float b2 = bv * bv, b3 = b2 * bv;
        const float invB = 1.0f / (float)BD;
        float acc = (float)BD * (pb[0] + pb[1] * bv + pb[2] * b2 + pb[3] * b3);
        acc += cs[6 * DD + o] * (pb[4] + pb[5] * bv + pb[6] * b2);
        acc += cs[7 * DD + o] * (pb[7] + pb[8] * bv);
        acc += cs[8 * DD + o] * pb[9];
        out[DD * DD + o] = invB * acc;
    }
}

// ---------------------------------------------------------------------------
// Fallback fp32 path (small workspace): colsum + gemm7 (verified round 1)
// ---------------------------------------------------------------------------
__global__ __launch_bounds__(256) void colsum_kernel(
    const float* __restrict__ x, const float* __restrict__ s,
    const float* __restrict__ y, float* __restrict__ cs)
{
    int c  = blockIdx.x * 256 + threadIdx.x;
    int r0 = blockIdx.y * 256;
    float xs1 = 0.f, xs2 = 0.f, xs3 = 0.f;
    float ss1 = 0.f, ss2 = 0.f, ss3 = 0.f;
    float ys1 = 0.f, ys2 = 0.f, ys3 = 0.f;
    float sy1 = 0.f, s2y = 0.f, sy2 = 0.f;
    for (int r = 0; r < 256; ++r) {
        size_t off = (size_t)(r0 + r) * DD + c;
        float xv = x[off], sv = s[off], yv = y[off];
        float xv2 = xv * xv; xs1 += xv; xs2 += xv2; xs3 += xv2 * xv;
        float sv2 = sv * sv; ss1 += sv; ss2 += sv2; ss3 += sv2 * sv;
        float yv2 = yv * yv; ys1 += yv; ys2 += yv2; ys3 += yv2 * yv;
        sy1 += sv * yv; s2y += sv2 * yv; sy2 += sv * yv2;
    }
    atomicAdd(&cs[0 * DD + c], xs1);  atomicAdd(&cs[1 * DD + c], xs2);  atomicAdd(&cs[2 * DD + c], xs3);
    atomicAdd(&cs[3 * DD + c], ss1);  atomicAdd(&cs[4 * DD + c], ss2);  atomicAdd(&cs[5 * DD + c], ss3);
    atomicAdd(&cs[6 * DD + c], ys1);  atomicAdd(&cs[7 * DD + c], ys2);  atomicAdd(&cs[8 * DD + c], ys3);
    atomicAdd(&cs[9 * DD + c], sy1);  atomicAdd(&cs[10 * DD + c], s2y); atomicAdd(&cs[11 * DD + c], sy2);
}

__global__ __launch_bounds__(256) void gemm7_kernel(
    const float* __restrict__ x, const float* __restrict__ s,
    const float* __restrict__ y, const float* __restrict__ w,
    const float* __restrict__ pw, float* __restrict__ out)
{
    __shared__ float lx[16][64];
    __shared__ float ls[16][64];
    __shared__ float ly[16][64];
    const int t  = threadIdx.x;
    const int tx = t & 15;
    const int ty = t >> 4;
    const int bid   = blockIdx.x;
    const int iBase = (bid & 7) * 64;
    const int oBase = ((bid >> 3) & 7) * 64;
    const int kBase = (bid >> 6) * 1024;
    const int srow  = t >> 4;
    const int scol  = (t & 15) * 4;

    float acc[7][4][4];
#pragma unroll
    for (int g = 0; g < 7; ++g)
#pragma unroll
        for (int r = 0; r < 4; ++r)
#pragma unroll
            for (int c = 0; c < 4; ++c) acc[g][r][c] = 0.f;

    for (int kt = 0; kt < 1024; kt += 16) {
        const size_t b = (size_t)(kBase + kt + srow);
        const float4 xv = *(const float4*)&x[b * DD + iBase + scol];
        const float4 sv = *(const float4*)&s[b * DD + oBase + scol];
        const float4 yv = *(const float4*)&y[b * DD + oBase + scol];
        __syncthreads();
        *(float4*)&lx[srow][scol] = xv;
        *(float4*)&ls[srow][scol] = sv;
        *(float4*)&ly[srow][scol] = yv;
        __syncthreads();
#pragma unroll
        for (int k = 0; k < 16; ++k) {
            const float4 xr = *(const float4*)&lx[k][tx * 4];
            const float4 sr = *(const float4*)&ls[k][ty * 4];
            const float4 yr = *(const float4*)&ly[k][ty * 4];
            float xa[4] = {xr.x, xr.y, xr.z, xr.w};
            float sa[4] = {sr.x, sr.y, sr.z, sr.w};
            float ya[4] = {yr.x, yr.y, yr.z, yr.w};
            float x2[4], s2[4], y2[4], syv[4];
#pragma unroll
            for (int c = 0; c < 4; ++c) x2[c] = xa[c] * xa[c];
#pragma unroll
            for (int r = 0; r < 4; ++r) {
                s2[r] = sa[r] * sa[r];
                y2[r] = ya[r] * ya[r];
                syv[r] = sa[r] * ya[r];
            }
#pragma unroll
            for (int r = 0; r < 4; ++r)
#pragma unroll
                for (int c = 0; c < 4; ++c) {
                    acc[0][r][c] += sa[r] * xa[c];
                    acc[1][r][c] += ya[r] * xa[c];
                    acc[2][r][c] += s2[r] * xa[c];
                    acc[3][r][c] += y2[r] * xa[c];
                    acc[4][r][c] += syv[r] * xa[c];
                    acc[5][r][c] += sa[r] * x2[c];
                    acc[6][r][c] += ya[r] * x2[c];
                }
        }
    }

    const float invB = 1.0f / (float)BD;
    const float p23 = pw[23], p24 = pw[24], p25 = pw[25], p26 = pw[26];
    const float p27 = pw[27], p28 = pw[28], p29 = pw[29], p32 = pw[32], p33 = pw[33];
#pragma unroll
    for (int r = 0; r < 4; ++r) {
        const int o = oBase + ty * 4 + r;
#pragma unroll
        for (int c = 0; c < 4; ++c) {
            const int i = iBase + tx * 4 + c;
            const float wv = w[o * DD + i];
            float contrib = acc[0][r][c] * (p26 + p27 * wv)
                          + acc[1][r][c] * (p23 + p24 * wv)
                          + acc[2][r][c] * p29
                          + acc[3][r][c] * p25
                          + acc[4][r][c] * p28
                          + acc[5][r][c] * p33
                          + acc[6][r][c] * p32;
            atomicAdd(&out[o * DD + i], invB * contrib);
        }
    }
}

extern "C" void kernel_launch(void* const* d_in, const int* in_sizes, int n_in,
                              void* d_out, int out_size, void* d_ws, size_t ws_size,
                              hipStream_t stream) {
    const float* x  = (const float*)d_in[0];
    const float* s  = (const float*)d_in[1];
    const float* y  = (const float*)d_in[2];
    const float* w  = (const float*)d_in[3];
    const float* b  = (const float*)d_in[4];
    const float* pw = (const float*)d_in[5];
    const float* pb = (const float*)d_in[6];
    float* out = (float*)d_out;

    const size_t planeBytes = (size_t)PLANE * 2 * NPLANES;   // ~41.9 MB
    const size_t csBytes    = 12 * DD * sizeof(float);

    if (ws_size >= planeBytes + csBytes) {
        unsigned short* pl = (unsigned short*)d_ws;
        float* cs = (float*)((char*)d_ws + planeBytes);
        hipMemsetAsync(cs, 0, csBytes, stream);
        hipMemsetAsync(out, 0, (size_t)out_size * sizeof(float), stream);
        prep_kernel<<<dim3(8, 64), 256, 0, stream>>>(x, s, y, pw, pl, cs);
        gemm3_kernel<<<dim3(16, 16, 3), 256, 0, stream>>>(pl, w, out);
        rank1_kernel<<<dim3((DD * DD) / 256), 256, 0, stream>>>(w, pw, cs, out);
        deltab_kernel<<<dim3(2), 256, 0, stream>>>(b, pb, cs, out);
    } else {
        float* cs = (float*)d_ws;
        hipMemsetAsync(cs, 0, csBytes, stream);
        hipMemsetAsync(out, 0, (size_t)out_size * sizeof(float), stream);
        colsum_kernel<<<dim3(2, 32), 256, 0, stream>>>(x, s, y, cs);
        gemm7_kernel<<<dim3(512), 256, 0, stream>>>(x, s, y, w, pw, out);
        rank1_kernel<<<dim3((DD * DD) / 256), 256, 0, stream>>>(w, pw, cs, out);
        deltab_kernel<<<dim3(2), 256, 0, stream>>>(b, pb, cs, out);
    }
}

// Round 3
// 160.213 us; speedup vs baseline: 2.8919x; 1.1226x over previous
//
#include <hip/hip_runtime.h>

#define BD 8192
#define DD 512
#define PLANE (BD * DD)          // 4194304 elems per bf16 plane
#define NPLANES 5                // 0:A1 1:A2 2:A3 3:x 4:x^2
#define KSPLIT 16
#define NELEM (DD * DD)          // 262144

typedef __attribute__((ext_vector_type(4))) float f32x4;
typedef __attribute__((ext_vector_type(8))) short short8;

__device__ __forceinline__ float polyev2(float c0, float c1, float c2, float w, float w2) {
    return c0 + c1 * w + c2 * w2;
}

// float -> bf16 bits, round-to-nearest-even
__device__ __forceinline__ unsigned short f2b(float v) {
    unsigned u = __builtin_bit_cast(unsigned, v);
    u += 0x7FFFu + ((u >> 16) & 1u);
    return (unsigned short)(u >> 16);
}

__device__ __forceinline__ void gload_lds16(const unsigned short* g, unsigned short* l) {
    __builtin_amdgcn_global_load_lds((__attribute__((address_space(1))) const void*)g,
                                     (__attribute__((address_space(3))) void*)l, 16, 0, 0);
}

// ===========================================================================
// FAST PATH
// Plane layout: plane[bt64][col][64k] bf16, 128B per col-row; within each row
// the 16B slot sigma is stored at physical slot sigma ^ (col & 7)  (XOR swizzle,
// involution, matched by the gemm read side; gload_lds stages bytes linearly).
// ===========================================================================

// prep2: grid (2,128), block 256. t -> colg = t&63 (4 cols), rsub = t>>6 (16 rows).
// Writes 5 planes + per-block column-sum partials csp[bt*2+ch][12][256].
__global__ __launch_bounds__(256) void prep2_kernel(
    const float* __restrict__ x, const float* __restrict__ s,
    const float* __restrict__ y, const float* __restrict__ pw,
    unsigned short* __restrict__ pl, float* __restrict__ csp)
{
    __shared__ float red[2][64][48];
    const int t    = threadIdx.x;
    const int colg = t & 63;
    const int rsub = t >> 6;              // 0..3
    const int ch   = blockIdx.x;          // column half
    const int bt   = blockIdx.y;          // bt64 tile 0..127
    const int c0   = ch * 256 + colg * 4;
    const int r0   = bt * 64 + rsub * 16;

    const float p23 = pw[23], p24 = pw[24], p25 = pw[25], p26 = pw[26], p27 = pw[27];
    const float p28 = pw[28], p29 = pw[29], p32 = pw[32], p33 = pw[33];

    float sm[12][4];
#pragma unroll
    for (int v = 0; v < 12; ++v)
#pragma unroll
        for (int cc = 0; cc < 4; ++cc) sm[v][cc] = 0.f;

#pragma unroll
    for (int w8 = 0; w8 < 2; ++w8) {      // two 8-row windows
        unsigned pk[NPLANES][4][4];       // [plane][cc][u32 of 16B slot]
#pragma unroll
        for (int j = 0; j < 8; ++j) {
            const int row = r0 + w8 * 8 + j;
            const float4 xv = *(const float4*)&x[(size_t)row * DD + c0];
            const float4 sv = *(const float4*)&s[(size_t)row * DD + c0];
            const float4 yv = *(const float4*)&y[(size_t)row * DD + c0];
            const float xa[4] = {xv.x, xv.y, xv.z, xv.w};
            const float sa[4] = {sv.x, sv.y, sv.z, sv.w};
            const float ya[4] = {yv.x, yv.y, yv.z, yv.w};
#pragma unroll
            for (int cc = 0; cc < 4; ++cc) {
                const float X = xa[cc], S = sa[cc], Y = ya[cc];
                const float X2 = X * X, S2 = S * S, Y2 = Y * Y, SY = S * Y;
                sm[0][cc] += X;  sm[1][cc] += X2;      sm[2][cc] += X2 * X;
                sm[3][cc] += S;  sm[4][cc] += S2;      sm[5][cc] += S2 * S;
                sm[6][cc] += Y;  sm[7][cc] += Y2;      sm[8][cc] += Y2 * Y;
                sm[9][cc] += SY; sm[10][cc] += S2 * Y; sm[11][cc] += S * Y2;
                unsigned short tv[NPLANES];
                tv[0] = f2b(p26 * S + p23 * Y + p29 * S2 + p25 * Y2 + p28 * SY);
                tv[1] = f2b(p33 * S + p32 * Y);
                tv[2] = f2b(p27 * S + p24 * Y);
                tv[3] = f2b(X);
                tv[4] = f2b(X2);
                if ((j & 1) == 0) {
#pragma unroll
                    for (int p = 0; p < NPLANES; ++p) pk[p][cc][j >> 1] = (unsigned)tv[p];
                } else {
#pragma unroll
                    for (int p = 0; p < NPLANES; ++p) pk[p][cc][j >> 1] |= (unsigned)tv[p] << 16;
                }
            }
        }
        // flush one 16B slot per (plane, col): slot sigma = rsub*2 + w8
#pragma unroll
        for (int p = 0; p < NPLANES; ++p) {
#pragma unroll
            for (int cc = 0; cc < 4; ++cc) {
                const int col = c0 + cc;
                const int sl  = (rsub * 2 + w8) ^ (col & 7);
                uint4 u;
                u.x = pk[p][cc][0]; u.y = pk[p][cc][1];
                u.z = pk[p][cc][2]; u.w = pk[p][cc][3];
                *(uint4*)&pl[(size_t)p * PLANE + ((size_t)bt * DD + col) * 64 + sl * 8] = u;
            }
        }
    }

    // block-level column-sum reduction (4 rsub -> 1), then one write per block
    if (rsub >= 2) {
#pragma unroll
        for (int v = 0; v < 12; ++v)
#pragma unroll
            for (int cc = 0; cc < 4; ++cc) red[rsub - 2][colg][v * 4 + cc] = sm[v][cc];
    }
    __syncthreads();
    if (rsub < 2) {
#pragma unroll
        for (int v = 0; v < 12; ++v)
#pragma unroll
            for (int cc = 0; cc < 4; ++cc) sm[v][cc] += red[rsub][colg][v * 4 + cc];
    }
    __syncthreads();
    if (rsub == 1) {
#pragma unroll
        for (int v = 0; v < 12; ++v)
#pragma unroll
            for (int cc = 0; cc < 4; ++cc) red[0][colg][v * 4 + cc] = sm[v][cc];
    }
    __syncthreads();
    if (rsub == 0) {
        const size_t pb = (size_t)bt * 2 + ch;
#pragma unroll
        for (int v = 0; v < 12; ++v)
#pragma unroll
            for (int cc = 0; cc < 4; ++cc)
                csp[(pb * 12 + v) * 256 + colg * 4 + cc] = sm[v][cc] + red[0][colg][v * 4 + cc];
    }
}

__global__ __launch_bounds__(256) void reduce_cs_kernel(
    const float* __restrict__ csp, float* __restrict__ cs)
{
    const int u = blockIdx.x * 256 + threadIdx.x;   // 0..6143 = 12*512
    if (u < 12 * DD) {
        const int v = u >> 9;
        const int c = u & 511;
        const int chh = c >> 8, cl = c & 255;
        float acc = 0.f;
        for (int bt = 0; bt < 128; ++bt)
            acc += csp[(((size_t)(bt * 2 + chh)) * 12 + v) * 256 + cl];
        cs[v * DD + c] = acc;
    }
}

// --------------------------- fused 2-acc GEMM ------------------------------
__device__ __forceinline__ void do_tile(
    const unsigned short* __restrict__ A, const unsigned short* __restrict__ B,
    int wo, int wi, int l15, int g4, f32x4 (&acc)[4][4])
{
#pragma unroll
    for (int ss = 0; ss < 2; ++ss) {
        short8 af[4], bf[4];
#pragma unroll
        for (int m = 0; m < 4; ++m) {
            const int r = wo + m * 16 + l15;
            af[m] = *(const short8*)((const char*)A + (r << 7) + ((((ss << 2) + g4) ^ (r & 7)) << 4));
        }
#pragma unroll
        for (int n = 0; n < 4; ++n) {
            const int r = wi + n * 16 + l15;
            bf[n] = *(const short8*)((const char*)B + (r << 7) + ((((ss << 2) + g4) ^ (r & 7)) << 4));
        }
#pragma unroll
        for (int m = 0; m < 4; ++m)
#pragma unroll
            for (int n = 0; n < 4; ++n)
                acc[m][n] = __builtin_amdgcn_mfma_f32_16x16x32_bf16(af[m], bf[n], acc[m][n], 0, 0, 0);
    }
}

__global__ __launch_bounds__(256) void gemm_kernel(
    const unsigned short* __restrict__ pl, const float* __restrict__ w,
    float* __restrict__ part)
{
    __shared__ unsigned short lds[2][2][8192];   // [buf][A/B] 16KB each

    const int t    = threadIdx.x;
    const int lane = t & 63;
    const int wid  = t >> 6;
    const int tileI = blockIdx.x & 3;
    const int tileO = blockIdx.x >> 2;
    const int ks    = blockIdx.y;
    const int wo = (wid >> 1) * 64, wi = (wid & 1) * 64;
    const int l15 = lane & 15, g4 = lane >> 4;

    const unsigned short* Am = pl + (size_t)(ks < 8 ? 0 : 1) * PLANE;
    const unsigned short* Bm = pl + (size_t)(ks < 8 ? 3 : 4) * PLANE;
    const unsigned short* Aw = pl + (size_t)2 * PLANE;
    const unsigned short* Bx = pl + (size_t)3 * PLANE;
    const int btm0 = (ks & 7) * 16;   // merged region bt64 base (16 tiles)
    const int btw0 = ks * 8;          // w-part bt64 base (8 tiles)

    f32x4 accM[4][4], accW[4][4];
#pragma unroll
    for (int m = 0; m < 4; ++m)
#pragma unroll
        for (int n = 0; n < 4; ++n) { accM[m][n] = (f32x4)0.f; accW[m][n] = (f32x4)0.f; }

    auto Abase = [&](int j) -> const unsigned short* {
        return (j < 16) ? Am + ((size_t)(btm0 + j) * DD + tileO * 128) * 64
                        : Aw + ((size_t)(btw0 + j - 16) * DD + tileO * 128) * 64;
    };
    auto Bbase = [&](int j) -> const unsigned short* {
        return (j < 16) ? Bm + ((size_t)(btm0 + j) * DD + tileI * 128) * 64
                        : Bx + ((size_t)(btw0 + j - 16) * DD + tileI * 128) * 64;
    };
    auto stage = [&](const unsigned short* Ag, const unsigned short* Bg, int buf) {
        unsigned short* La = &lds[buf][0][0];
        unsigned short* Lb = &lds[buf][1][0];
#pragma unroll
        for (int c = 0; c < 4; ++c) {
            gload_lds16(Ag + c * 2048 + t * 8, La + c * 2048 + wid * 512);
            gload_lds16(Bg + c * 2048 + t * 8, Lb + c * 2048 + wid * 512);
        }
    };

    stage(Abase(0), Bbase(0), 0);
    __syncthreads();
#pragma unroll 1
    for (int j = 0; j < 16; ++j) {
        const int cur = j & 1;
        stage(Abase(j + 1), Bbase(j + 1), cur ^ 1);    // j+1 == 16 rolls into W region
        do_tile(&lds[cur][0][0], &lds[cur][1][0], wo, wi, l15, g4, accM);
        __syncthreads();
    }
#pragma unroll 1
    for (int j = 16; j < 24; ++j) {
        const int cur = j & 1;
        if (j < 23) stage(Abase(j + 1), Bbase(j + 1), cur ^ 1);
        do_tile(&lds[cur][0][0], &lds[cur][1][0], wo, wi, l15, g4, accW);
        __syncthreads();
    }

    float* pout = part + (size_t)ks * NELEM;
#pragma unroll
    for (int m = 0; m < 4; ++m) {
        const int o = tileO * 128 + wo + m * 16 + g4 * 4;
#pragma unroll
        for (int n = 0; n < 4; ++n) {
            const int i = tileI * 128 + wi + n * 16 + l15;
#pragma unroll
            for (int r = 0; r < 4; ++r) {
                const float wv = w[(size_t)(o + r) * DD + i];
                pout[(size_t)(o + r) * DD + i] = accM[m][n][r] + wv * accW[m][n][r];
            }
        }
    }
}

// reduce partials + rank-1/const terms, single write (no atomics, no memset)
__global__ __launch_bounds__(256) void reduce_rank1_kernel(
    const float* __restrict__ part, const float* __restrict__ w,
    const float* __restrict__ pw, const float* __restrict__ cs,
    float* __restrict__ out)
{
    const int idx = blockIdx.x * 256 + threadIdx.x;   // 0..262143
    const int o = idx >> 9;
    const int i = idx & 511;
    float g = 0.f;
#pragma unroll
    for (int ks = 0; ks < KSPLIT; ++ks) g += part[(size_t)ks * NELEM + idx];
    const float wv = w[idx];
    const float w2 = wv * wv, w3 = w2 * wv;
    float acc = (float)BD * (pw[0] + pw[1] * wv + pw[2] * w2 + pw[3] * w3);
    acc += cs[0 * DD + i] * polyev2(pw[20], pw[21], pw[22], wv, w2);  // x
    acc += cs[1 * DD + i] * (pw[30] + pw[31] * wv);                   // x^2
    acc += cs[2 * DD + i] * pw[34];                                   // x^3
    acc += cs[6 * DD + o]  * polyev2(pw[4],  pw[5],  pw[6],  wv, w2); // y
    acc += cs[7 * DD + o]  * (pw[7] + pw[8] * wv);                    // y^2
    acc += cs[8 * DD + o]  * pw[9];                                   // y^3
    acc += cs[3 * DD + o]  * polyev2(pw[10], pw[11], pw[12], wv, w2); // s
    acc += cs[9 * DD + o]  * (pw[13] + pw[14] * wv);                  // s*y
    acc += cs[11 * DD + o] * pw[15];                                  // s*y^2
    acc += cs[4 * DD + o]  * (pw[16] + pw[17] * wv);                  // s^2
    acc += cs[10 * DD + o] * pw[18];                                  // s^2*y
    acc += cs[5 * DD + o]  * pw[19];                                  // s^3
    out[idx] = (1.0f / (float)BD) * (g + acc);
}

__global__ __launch_bounds__(256) void deltab_kernel(
    const float* __restrict__ bvec, const float* __restrict__ pb,
    const float* __restrict__ cs, float* __restrict__ out)
{
    const int o = blockIdx.x * 256 + threadIdx.x;
    if (o < DD) {
        const float bv = bvec[o];
        const float b2 = bv * bv, b3 = b2 * bv;
        const float invB = 1.0f / (float)BD;
        float acc = (float)BD * (pb[0] + pb[1] * bv + pb[2] * b2 + pb[3] * b3);
        acc += cs[6 * DD + o] * (pb[4] + pb[5] * bv + pb[6] * b2);
        acc += cs[7 * DD + o] * (pb[7] + pb[8] * bv);
        acc += cs[8 * DD + o] * pb[9];
        out[DD * DD + o] = invB * acc;
    }
}

// ===========================================================================
// FALLBACK (round-2 verified path; used only if ws too small for fast path)
// ===========================================================================
__global__ __launch_bounds__(256) void prep_old_kernel(
    const float* __restrict__ x, const float* __restrict__ s,
    const float* __restrict__ y, const float* __restrict__ pw,
    unsigned short* __restrict__ pl, float* __restrict__ cs)
{
    const int t  = threadIdx.x;
    const int o  = blockIdx.x * 64 + (t & 63);
    const int bt = blockIdx.y * 4 + (t >> 6);
    const int b0 = bt * 32;
    const float p23 = pw[23], p24 = pw[24], p25 = pw[25], p26 = pw[26], p27 = pw[27];
    const float p28 = pw[28], p29 = pw[29], p32 = pw[32], p33 = pw[33];
    float xs1 = 0.f, xs2 = 0.f, xs3 = 0.f;
    float ss1 = 0.f, ss2 = 0.f, ss3 = 0.f;
    float ys1 = 0.f, ys2 = 0.f, ys3 = 0.f;
    float sy1 = 0.f, s2y = 0.f, sy2 = 0.f;
    unsigned pk[NPLANES][16];
#pragma unroll
    for (int j = 0; j < 32; ++j) {
        const size_t off = (size_t)(b0 + j) * DD + o;
        const float xv = x[off], sv = s[off], yv = y[off];
        const float xq = xv * xv, sq = sv * sv, yq = yv * yv, syv = sv * yv;
        xs1 += xv;  xs2 += xq;      xs3 += xq * xv;
        ss1 += sv;  ss2 += sq;      ss3 += sq * sv;
        ys1 += yv;  ys2 += yq;      ys3 += yq * yv;
        sy1 += syv; s2y += sq * yv; sy2 += sv * yq;
        unsigned short tmp[NPLANES];
        tmp[0] = f2b(p26 * sv + p23 * yv + p29 * sq + p25 * yq + p28 * syv);
        tmp[1] = f2b(p33 * sv + p32 * yv);
        tmp[2] = f2b(p27 * sv + p24 * yv);
        tmp[3] = f2b(xv);
        tmp[4] = f2b(xq);
        if ((j & 1) == 0) {
#pragma unroll
            for (int p = 0; p < NPLANES; ++p) pk[p][j >> 1] = (unsigned)tmp[p];
        } else {
#pragma unroll
            for (int p = 0; p < NPLANES; ++p) pk[p][j >> 1] |= (unsigned)tmp[p] << 16;
        }
    }
    const size_t wbase = ((size_t)bt * DD + o) * 32;
#pragma unroll
    for (int p = 0; p < NPLANES; ++p) {
        uint4* dst = (uint4*)(pl + (size_t)p * PLANE + wbase);
#pragma unroll
        for (int c = 0; c < 4; ++c) {
            uint4 u;
            u.x = pk[p][c * 4 + 0]; u.y = pk[p][c * 4 + 1];
            u.z = pk[p][c * 4 + 2]; u.w = pk[p][c * 4 + 3];
            dst[c] = u;
        }
    }
    atomicAdd(&cs[0 * DD + o], xs1);  atomicAdd(&cs[1 * DD + o], xs2);  atomicAdd(&cs[2 * DD + o], xs3);
    atomicAdd(&cs[3 * DD + o], ss1);  atomicAdd(&cs[4 * DD + o], ss2);  atomicAdd(&cs[5 * DD + o], ss3);
    atomicAdd(&cs[6 * DD + o], ys1);  atomicAdd(&cs[7 * DD + o], ys2);  atomicAdd(&cs[8 * DD + o], ys3);
    atomicAdd(&cs[9 * DD + o], sy1);  atomicAdd(&cs[10 * DD + o], s2y); atomicAdd(&cs[11 * DD + o], sy2);
}

__global__ __launch_bounds__(256) void gemm3_kernel(
    const unsigned short* __restrict__ pl, const float* __restrict__ w,
    float* __restrict__ out)
{
    __shared__ unsigned short ldsA[128 * 32];
    __shared__ unsigned short ldsB[128 * 32];
    const int t    = threadIdx.x;
    const int lane = t & 63;
    const int wid  = t >> 6;
    const int g     = blockIdx.z;
    const int tileI = blockIdx.x & 3;
    const int tileO = blockIdx.x >> 2;
    const int kt0   = blockIdx.y * 16;
    const int aplane = (g == 0) ? 0 : (g == 1) ? 1 : 2;
    const int bplane = (g == 1) ? 4 : 3;
    const unsigned short* Ap = pl + (size_t)aplane * PLANE;
    const unsigned short* Bp = pl + (size_t)bplane * PLANE;
    const int wo = (wid >> 1) * 64;
    const int wi = (wid & 1) * 64;
    const int l15 = lane & 15;
    const int kchunk = (lane >> 4) * 8;
    f32x4 acc[4][4];
#pragma unroll
    for (int m = 0; m < 4; ++m)
#pragma unroll
        for (int n = 0; n < 4; ++n) acc[m][n] = (f32x4)0.f;
    unsigned short* ldsAw = ldsA + wid * 512;
    unsigned short* ldsBw = ldsB + wid * 512;
    const size_t tg = (size_t)t * 8;
    for (int kt = 0; kt < 16; ++kt) {
        const size_t abase = ((size_t)(kt0 + kt) * DD + tileO * 128) * 32;
        const size_t bbase = ((size_t)(kt0 + kt) * DD + tileI * 128) * 32;
        __syncthreads();
        gload_lds16(Ap + abase + tg,        ldsAw);
        gload_lds16(Ap + abase + 2048 + tg, ldsAw + 2048);
        gload_lds16(Bp + bbase + tg,        ldsBw);
        gload_lds16(Bp + bbase + 2048 + tg, ldsBw + 2048);
        __syncthreads();
        short8 af[4], bf[4];
#pragma unroll
        for (int m = 0; m < 4; ++m)
            af[m] = *(const short8*)&ldsA[(wo + m * 16 + l15) * 32 + kchunk];
#pragma unroll
        for (int n = 0; n < 4; ++n)
            bf[n] = *(const short8*)&ldsB[(wi + n * 16 + l15) * 32 + kchunk];
#pragma unroll
        for (int m = 0; m < 4; ++m)
#pragma unroll
            for (int n = 0; n < 4; ++n)
                acc[m][n] = __builtin_amdgcn_mfma_f32_16x16x32_bf16(af[m], bf[n], acc[m][n], 0, 0, 0);
    }
    const float invB = 1.0f / (float)BD;
    const int l4 = lane >> 4;
#pragma unroll
    for (int m = 0; m < 4; ++m) {
#pragma unroll
        for (int n = 0; n < 4; ++n) {
#pragma unroll
            for (int r = 0; r < 4; ++r) {
                const int o = tileO * 128 + wo + m * 16 + l4 * 4 + r;
                const int i = tileI * 128 + wi + n * 16 + l15;
                float v = acc[m][n][r] * invB;
                if (g == 2) v *= w[o * DD + i];
                atomicAdd(&out[o * DD + i], v);
            }
        }
    }
}

__global__ __launch_bounds__(256) void rank1_kernel(
    const float* __restrict__ w, const float* __restrict__ pw,
    const float* __restrict__ cs, float* __restrict__ out)
{
    const int idx = blockIdx.x * 256 + threadIdx.x;
    const int o = idx >> 9;
    const int i = idx & 511;
    const float wv = w[idx];
    const float w2 = wv * wv, w3 = w2 * wv;
    const float invB = 1.0f / (float)BD;
    float acc = (float)BD * (pw[0] + pw[1] * wv + pw[2] * w2 + pw[3] * w3);
    acc += cs[0 * DD + i] * polyev2(pw[20], pw[21], pw[22], wv, w2);
    acc += cs[1 * DD + i] * (pw[30] + pw[31] * wv);
    acc += cs[2 * DD + i] * pw[34];
    acc += cs[6 * DD + o]  * polyev2(pw[4],  pw[5],  pw[6],  wv, w2);
    acc += cs[7 * DD + o]  * (pw[7] + pw[8] * wv);
    acc += cs[8 * DD + o]  * pw[9];
    acc += cs[3 * DD + o]  * polyev2(pw[10], pw[11], pw[12], wv, w2);
    acc += cs[9 * DD + o]  * (pw[13] + pw[14] * wv);
    acc += cs[11 * DD + o] * pw[15];
    acc += cs[4 * DD + o]  * (pw[16] + pw[17] * wv);
    acc += cs[10 * DD + o] * pw[18];
    acc += cs[5 * DD + o]  * pw[19];
    out[idx] += invB * acc;
}

extern "C" void kernel_launch(void* const* d_in, const int* in_sizes, int n_in,
                              void* d_out, int out_size, void* d_ws, size_t ws_size,
                              hipStream_t stream) {
    const float* x  = (const float*)d_in[0];
    const float* s  = (const float*)d_in[1];
    const float* y  = (const float*)d_in[2];
    const float* w  = (const float*)d_in[3];
    const float* b  = (const float*)d_in[4];
    const float* pw = (const float*)d_in[5];
    const float* pb = (const float*)d_in[6];
    float* out = (float*)d_out;

    const size_t planeBytes = (size_t)PLANE * 2 * NPLANES;            // 41.9 MB
    const size_t partBytes  = (size_t)KSPLIT * NELEM * sizeof(float); // 16.8 MB
    const size_t cspBytes   = (size_t)256 * 12 * 256 * sizeof(float); //  3.1 MB
    const size_t csBytes    = 12 * DD * sizeof(float);

    if (ws_size >= planeBytes + partBytes + cspBytes + csBytes) {
        unsigned short* pl = (unsigned short*)d_ws;
        float* part = (float*)((char*)d_ws + planeBytes);
        float* csp  = (float*)((char*)d_ws + planeBytes + partBytes);
        float* cs   = (float*)((char*)d_ws + planeBytes + partBytes + cspBytes);
        prep2_kernel<<<dim3(2, 128), 256, 0, stream>>>(x, s, y, pw, pl, csp);
        reduce_cs_kernel<<<24, 256, 0, stream>>>(csp, cs);
        gemm_kernel<<<dim3(16, 16), 256, 0, stream>>>(pl, w, part);
        reduce_rank1_kernel<<<1024, 256, 0, stream>>>(part, w, pw, cs, out);
        deltab_kernel<<<2, 256, 0, stream>>>(b, pb, cs, out);
    } else {
        unsigned short* pl = (unsigned short*)d_ws;
        float* cs = (float*)((char*)d_ws + planeBytes);
        hipMemsetAsync(cs, 0, csBytes, stream);
        hipMemsetAsync(out, 0, (size_t)out_size * sizeof(float), stream);
        prep_old_kernel<<<dim3(8, 64), 256, 0, stream>>>(x, s, y, pw, pl, cs);
        gemm3_kernel<<<dim3(16, 16, 3), 256, 0, stream>>>(pl, w, out);
        rank1_kernel<<<dim3((DD * DD) / 256), 256, 0, stream>>>(w, pw, cs, out);
        deltab_kernel<<<2, 256, 0, stream>>>(b, pb, cs, out);
    }
}

// Round 4
// 138.112 us; speedup vs baseline: 3.3547x; 1.1600x over previous
//
#include <hip/hip_runtime.h>

#define BD 8192
#define DD 512
#define PLANE (BD * DD)          // 4194304 elems per bf16 plane
#define NPLANES 5                // 0:A1 1:A2 2:A3 3:x 4:x^2
#define KSPLIT 32
#define NELEM (DD * DD)          // 262144

typedef __attribute__((ext_vector_type(4))) float f32x4;
typedef __attribute__((ext_vector_type(8))) short short8;

__device__ __forceinline__ float polyev2(float c0, float c1, float c2, float w, float w2) {
    return c0 + c1 * w + c2 * w2;
}

// float -> bf16 bits, round-to-nearest-even
__device__ __forceinline__ unsigned short f2b(float v) {
    unsigned u = __builtin_bit_cast(unsigned, v);
    u += 0x7FFFu + ((u >> 16) & 1u);
    return (unsigned short)(u >> 16);
}

__device__ __forceinline__ void gload_lds16(const unsigned short* g, unsigned short* l) {
    __builtin_amdgcn_global_load_lds((__attribute__((address_space(1))) const void*)g,
                                     (__attribute__((address_space(3))) void*)l, 16, 0, 0);
}

// ===========================================================================
// FAST PATH
// Plane layout (bf16): elem addr = p*PLANE + (bt*512 + C)*64 + ((k>>3)^(C&7))*8 + (k&7)
//   bt = K-tile of 64 rows, C = column (o for A-planes / i for B-planes), k = row%64.
//   XOR slot swizzle makes gemm's ds_read_b128 column-slice reads conflict-free;
//   gload_lds stages bytes linearly so the global image IS the LDS image.
// ===========================================================================

// prep3: block = 64 rows x 64 cols. Builds the 5 plane sub-images in LDS, then
// copies LDS->global contiguously (1KB/wave stores). Column sums folded in.
// grid (8 colq, 128 bt), block 256. VGPR-capped for 3 waves/SIMD.
__global__ __launch_bounds__(256, 3) void prep3_kernel(
    const float* __restrict__ x, const float* __restrict__ s,
    const float* __restrict__ y, const float* __restrict__ pw,
    unsigned short* __restrict__ pl, float* __restrict__ csp)
{
    __shared__ char L[5 * 8192];          // 40 KB plane image; reused for reduction

    const int t      = threadIdx.x;
    const int colL4  = (t & 15) * 4;      // 4 consecutive cols
    const int rg     = t >> 4;            // 0..15 -> rows kl..kl+3
    const int kl     = rg * 4;
    const int c0     = blockIdx.x * 64;   // column base (multiple of 64)
    const int bt     = blockIdx.y;        // K-tile (64 rows)
    const int r0     = bt * 64;

    const float p23 = pw[23], p24 = pw[24], p25 = pw[25], p26 = pw[26], p27 = pw[27];
    const float p28 = pw[28], p29 = pw[29], p32 = pw[32], p33 = pw[33];

    float sm[12][4];
#pragma unroll
    for (int v = 0; v < 12; ++v)
#pragma unroll
        for (int cc = 0; cc < 4; ++cc) sm[v][cc] = 0.f;

    unsigned pk[NPLANES][4][2];           // [plane][cc][2 u32 = 4 bf16 rows]

#pragma unroll
    for (int j = 0; j < 4; ++j) {
        const int row = r0 + kl + j;
        const float4 xv = *(const float4*)&x[(size_t)row * DD + c0 + colL4];
        const float4 sv = *(const float4*)&s[(size_t)row * DD + c0 + colL4];
        const float4 yv = *(const float4*)&y[(size_t)row * DD + c0 + colL4];
        const float xa[4] = {xv.x, xv.y, xv.z, xv.w};
        const float sa[4] = {sv.x, sv.y, sv.z, sv.w};
        const float ya[4] = {yv.x, yv.y, yv.z, yv.w};
#pragma unroll
        for (int cc = 0; cc < 4; ++cc) {
            const float X = xa[cc], S = sa[cc], Y = ya[cc];
            const float X2 = X * X, S2 = S * S, Y2 = Y * Y, SY = S * Y;
            sm[0][cc] += X;  sm[1][cc] += X2;      sm[2][cc] += X2 * X;
            sm[3][cc] += S;  sm[4][cc] += S2;      sm[5][cc] += S2 * S;
            sm[6][cc] += Y;  sm[7][cc] += Y2;      sm[8][cc] += Y2 * Y;
            sm[9][cc] += SY; sm[10][cc] += S2 * Y; sm[11][cc] += S * Y2;
            unsigned short tv[NPLANES];
            tv[0] = f2b(p26 * S + p23 * Y + p29 * S2 + p25 * Y2 + p28 * SY);
            tv[1] = f2b(p33 * S + p32 * Y);
            tv[2] = f2b(p27 * S + p24 * Y);
            tv[3] = f2b(X);
            tv[4] = f2b(X2);
            if ((j & 1) == 0) {
#pragma unroll
                for (int p = 0; p < NPLANES; ++p) pk[p][cc][j >> 1] = (unsigned)tv[p];
            } else {
#pragma unroll
                for (int p = 0; p < NPLANES; ++p) pk[p][cc][j >> 1] |= (unsigned)tv[p] << 16;
            }
        }
    }

    // write 8B (4 rows of bf16) per (plane,col) into the swizzled LDS image
#pragma unroll
    for (int p = 0; p < NPLANES; ++p) {
#pragma unroll
        for (int cc = 0; cc < 4; ++cc) {
            const int colL = colL4 + cc;
            const int addr = p * 8192 + colL * 128 + (((kl >> 3) ^ (colL & 7)) << 4) + ((kl & 4) << 1);
            uint2 u; u.x = pk[p][cc][0]; u.y = pk[p][cc][1];
            *(uint2*)&L[addr] = u;
        }
    }
    __syncthreads();

    // contiguous LDS -> global copy: 10 x 16B per thread, 1KB per wave-instr
    {
        char* gbase = (char*)pl;                       // plane p at p*PLANE*2
        const size_t blockByte = ((size_t)bt * DD + c0) * 128;  // within each plane
#pragma unroll
        for (int u = 0; u < 10; ++u) {
            const int byteoff = u * 4096 + t * 16;     // 0..40944
            const int p = byteoff >> 13;
            const int within = byteoff & 8191;
            *(uint4*)(gbase + ((size_t)p * PLANE) * 2 + blockByte + within) =
                *(const uint4*)&L[byteoff];
        }
    }
    __syncthreads();

    // column-sum reduction: in-wave over rg (lanes ^16, ^32), cross-wave via LDS
#pragma unroll
    for (int v = 0; v < 12; ++v)
#pragma unroll
        for (int cc = 0; cc < 4; ++cc) {
            sm[v][cc] += __shfl_xor(sm[v][cc], 16, 64);
            sm[v][cc] += __shfl_xor(sm[v][cc], 32, 64);
        }
    float* R = (float*)L;
    const int wv = t >> 6, ln = t & 63;
    if (ln < 16) {
#pragma unroll
        for (int v = 0; v < 12; ++v)
#pragma unroll
            for (int cc = 0; cc < 4; ++cc)
                R[(wv * 16 + ln) * 48 + v * 4 + cc] = sm[v][cc];
    }
    __syncthreads();
    if (t < 16) {
        const int blk = bt * 8 + blockIdx.x;
#pragma unroll
        for (int v = 0; v < 12; ++v)
#pragma unroll
            for (int cc = 0; cc < 4; ++cc) {
                float a = R[(0 * 16 + t) * 48 + v * 4 + cc]
                        + R[(1 * 16 + t) * 48 + v * 4 + cc]
                        + R[(2 * 16 + t) * 48 + v * 4 + cc]
                        + R[(3 * 16 + t) * 48 + v * 4 + cc];
                csp[((size_t)blk * 12 + v) * 64 + t * 4 + cc] = a;
            }
    }
}

// cs[v][c] = sum over 128 bt-partials
__global__ __launch_bounds__(256) void reduce_cs_kernel(
    const float* __restrict__ csp, float* __restrict__ cs)
{
    const int u = blockIdx.x * 256 + threadIdx.x;   // 0..6143 = 12*512
    if (u < 12 * DD) {
        const int v = u >> 9;
        const int c = u & 511;
        const int colq = c >> 6, cl = c & 63;
        float acc = 0.f;
        for (int bt = 0; bt < 128; ++bt)
            acc += csp[((size_t)(bt * 8 + colq) * 12 + v) * 64 + cl];
        cs[v * DD + c] = acc;
    }
}

// --------------------------- fused 2-acc GEMM ------------------------------
__device__ __forceinline__ void do_tile(
    const unsigned short* __restrict__ A, const unsigned short* __restrict__ B,
    int wo, int wi, int l15, int g4, f32x4 (&acc)[4][4])
{
#pragma unroll
    for (int ss = 0; ss < 2; ++ss) {
        short8 af[4], bf[4];
#pragma unroll
        for (int m = 0; m < 4; ++m) {
            const int r = wo + m * 16 + l15;
            af[m] = *(const short8*)((const char*)A + (r << 7) + ((((ss << 2) + g4) ^ (r & 7)) << 4));
        }
#pragma unroll
        for (int n = 0; n < 4; ++n) {
            const int r = wi + n * 16 + l15;
            bf[n] = *(const short8*)((const char*)B + (r << 7) + ((((ss << 2) + g4) ^ (r & 7)) << 4));
        }
#pragma unroll
        for (int m = 0; m < 4; ++m)
#pragma unroll
            for (int n = 0; n < 4; ++n)
                acc[m][n] = __builtin_amdgcn_mfma_f32_16x16x32_bf16(af[m], bf[n], acc[m][n], 0, 0, 0);
    }
}

// grid 512 (1D). ks = (bid&7) + 8*(bid>>7) groups same-ks blocks on one XCD
// (heuristic: dispatch round-robins wg%8 across XCDs; bijective either way).
// Per block: 8 merged K-steps (A1@x | A2@x2 halves) + 4 w-steps (A3@x).
__global__ __launch_bounds__(256, 2) void gemm_kernel(
    const unsigned short* __restrict__ pl, const float* __restrict__ w,
    float* __restrict__ part)
{
    __shared__ unsigned short lds[2][2][8192];   // [buf][A/B] 16KB each

    const int t    = threadIdx.x;
    const int lane = t & 63;
    const int wid  = t >> 6;
    const int bid  = blockIdx.x;
    const int ks   = (bid & 7) + ((bid >> 7) << 3);   // 0..31
    const int tile = (bid >> 3) & 15;
    const int tileI = tile & 3;
    const int tileO = tile >> 2;
    const int wo = (wid >> 1) * 64, wi = (wid & 1) * 64;
    const int l15 = lane & 15, g4 = lane >> 4;

    const unsigned short* Am = pl + (size_t)(ks < 16 ? 0 : 1) * PLANE;
    const unsigned short* Bm = pl + (size_t)(ks < 16 ? 3 : 4) * PLANE;
    const unsigned short* Aw = pl + (size_t)2 * PLANE;
    const unsigned short* Bx = pl + (size_t)3 * PLANE;
    const int btm0 = (ks & 15) * 8;   // merged region: 8 bt64 tiles (K=512)
    const int btw0 = ks * 4;          // w region: 4 bt64 tiles (K=256)

    f32x4 accM[4][4], accW[4][4];
#pragma unroll
    for (int m = 0; m < 4; ++m)
#pragma unroll
        for (int n = 0; n < 4; ++n) { accM[m][n] = (f32x4)0.f; accW[m][n] = (f32x4)0.f; }

    auto Abase = [&](int j) -> const unsigned short* {
        return (j < 8) ? Am + ((size_t)(btm0 + j) * DD + tileO * 128) * 64
                       : Aw + ((size_t)(btw0 + j - 8) * DD + tileO * 128) * 64;
    };
    auto Bbase = [&](int j) -> const unsigned short* {
        return (j < 8) ? Bm + ((size_t)(btm0 + j) * DD + tileI * 128) * 64
                       : Bx + ((size_t)(btw0 + j - 8) * DD + tileI * 128) * 64;
    };
    auto stage = [&](const unsigned short* Ag, const unsigned short* Bg, int buf) {
        unsigned short* La = &lds[buf][0][0];
        unsigned short* Lb = &lds[buf][1][0];
#pragma unroll
        for (int c = 0; c < 4; ++c) {
            gload_lds16(Ag + c * 2048 + t * 8, La + c * 2048 + wid * 512);
            gload_lds16(Bg + c * 2048 + t * 8, Lb + c * 2048 + wid * 512);
        }
    };

    stage(Abase(0), Bbase(0), 0);
    __syncthreads();
#pragma unroll 1
    for (int j = 0; j < 8; ++j) {
        const int cur = j & 1;
        stage(Abase(j + 1), Bbase(j + 1), cur ^ 1);    // j+1==8 rolls into W region
        do_tile(&lds[cur][0][0], &lds[cur][1][0], wo, wi, l15, g4, accM);
        __syncthreads();
    }
#pragma unroll 1
    for (int j = 8; j < 12; ++j) {
        const int cur = j & 1;
        if (j < 11) stage(Abase(j + 1), Bbase(j + 1), cur ^ 1);
        do_tile(&lds[cur][0][0], &lds[cur][1][0], wo, wi, l15, g4, accW);
        __syncthreads();
    }

    float* pout = part + (size_t)ks * NELEM;
#pragma unroll
    for (int m = 0; m < 4; ++m) {
        const int o = tileO * 128 + wo + m * 16 + g4 * 4;
#pragma unroll
        for (int n = 0; n < 4; ++n) {
            const int i = tileI * 128 + wi + n * 16 + l15;
#pragma unroll
            for (int r = 0; r < 4; ++r) {
                const float wv = w[(size_t)(o + r) * DD + i];
                pout[(size_t)(o + r) * DD + i] = accM[m][n][r] + wv * accW[m][n][r];
            }
        }
    }
}

// reduce partials + rank-1/const terms, single coalesced write (no atomics)
__global__ __launch_bounds__(256) void reduce_rank1_kernel(
    const float* __restrict__ part, const float* __restrict__ w,
    const float* __restrict__ pw, const float* __restrict__ cs,
    float* __restrict__ out)
{
    const int idx = blockIdx.x * 256 + threadIdx.x;   // 0..262143
    const int o = idx >> 9;
    const int i = idx & 511;
    float g = 0.f;
#pragma unroll
    for (int ks = 0; ks < KSPLIT; ++ks) g += part[(size_t)ks * NELEM + idx];
    const float wv = w[idx];
    const float w2 = wv * wv, w3 = w2 * wv;
    float acc = (float)BD * (pw[0] + pw[1] * wv + pw[2] * w2 + pw[3] * w3);
    acc += cs[0 * DD + i] * polyev2(pw[20], pw[21], pw[22], wv, w2);  // x
    acc += cs[1 * DD + i] * (pw[30] + pw[31] * wv);                   // x^2
    acc += cs[2 * DD + i] * pw[34];                                   // x^3
    acc += cs[6 * DD + o]  * polyev2(pw[4],  pw[5],  pw[6],  wv, w2); // y
    acc += cs[7 * DD + o]  * (pw[7] + pw[8] * wv);                    // y^2
    acc += cs[8 * DD + o]  * pw[9];                                   // y^3
    acc += cs[3 * DD + o]  * polyev2(pw[10], pw[11], pw[12], wv, w2); // s
    acc += cs[9 * DD + o]  * (pw[13] + pw[14] * wv);                  // s*y
    acc += cs[11 * DD + o] * pw[15];                                  // s*y^2
    acc += cs[4 * DD + o]  * (pw[16] + pw[17] * wv);                  // s^2
    acc += cs[10 * DD + o] * pw[18];                                  // s^2*y
    acc += cs[5 * DD + o]  * pw[19];                                  // s^3
    out[idx] = (1.0f / (float)BD) * (g + acc);
}

__global__ __launch_bounds__(256) void deltab_kernel(
    const float* __restrict__ bvec, const float* __restrict__ pb,
    const float* __restrict__ cs, float* __restrict__ out)
{
    const int o = blockIdx.x * 256 + threadIdx.x;
    if (o < DD) {
        const float bv = bvec[o];
        const float b2 = bv * bv, b3 = b2 * bv;
        const float invB = 1.0f / (float)BD;
        float acc = (float)BD * (pb[0] + pb[1] * bv + pb[2] * b2 + pb[3] * b3);
        acc += cs[6 * DD + o] * (pb[4] + pb[5] * bv + pb[6] * b2);
        acc += cs[7 * DD + o] * (pb[7] + pb[8] * bv);
        acc += cs[8 * DD + o] * pb[9];
        out[DD * DD + o] = invB * acc;
    }
}

// ===========================================================================
// FALLBACK (round-2 verified path; used only if ws too small for fast path)
// ===========================================================================
__global__ __launch_bounds__(256) void prep_old_kernel(
    const float* __restrict__ x, const float* __restrict__ s,
    const float* __restrict__ y, const float* __restrict__ pw,
    unsigned short* __restrict__ pl, float* __restrict__ cs)
{
    const int t  = threadIdx.x;
    const int o  = blockIdx.x * 64 + (t & 63);
    const int bt = blockIdx.y * 4 + (t >> 6);
    const int b0 = bt * 32;
    const float p23 = pw[23], p24 = pw[24], p25 = pw[25], p26 = pw[26], p27 = pw[27];
    const float p28 = pw[28], p29 = pw[29], p32 = pw[32], p33 = pw[33];
    float xs1 = 0.f, xs2 = 0.f, xs3 = 0.f;
    float ss1 = 0.f, ss2 = 0.f, ss3 = 0.f;
    float ys1 = 0.f, ys2 = 0.f, ys3 = 0.f;
    float sy1 = 0.f, s2y = 0.f, sy2 = 0.f;
    unsigned pk[NPLANES][16];
#pragma unroll
    for (int j = 0; j < 32; ++j) {
        const size_t off = (size_t)(b0 + j) * DD + o;
        const float xv = x[off], sv = s[off], yv = y[off];
        const float xq = xv * xv, sq = sv * sv, yq = yv * yv, syv = sv * yv;
        xs1 += xv;  xs2 += xq;      xs3 += xq * xv;
        ss1 += sv;  ss2 += sq;      ss3 += sq * sv;
        ys1 += yv;  ys2 += yq;      ys3 += yq * yv;
        sy1 += syv; s2y += sq * yv; sy2 += sv * yq;
        unsigned short tmp[NPLANES];
        tmp[0] = f2b(p26 * sv + p23 * yv + p29 * sq + p25 * yq + p28 * syv);
        tmp[1] = f2b(p33 * sv + p32 * yv);
        tmp[2] = f2b(p27 * sv + p24 * yv);
        tmp[3] = f2b(xv);
        tmp[4] = f2b(xq);
        if ((j & 1) == 0) {
#pragma unroll
            for (int p = 0; p < NPLANES; ++p) pk[p][j >> 1] = (unsigned)tmp[p];
        } else {
#pragma unroll
            for (int p = 0; p < NPLANES; ++p) pk[p][j >> 1] |= (unsigned)tmp[p] << 16;
        }
    }
    const size_t wbase = ((size_t)bt * DD + o) * 32;
#pragma unroll
    for (int p = 0; p < NPLANES; ++p) {
        uint4* dst = (uint4*)(pl + (size_t)p * PLANE + wbase);
#pragma unroll
        for (int c = 0; c < 4; ++c) {
            uint4 u;
            u.x = pk[p][c * 4 + 0]; u.y = pk[p][c * 4 + 1];
            u.z = pk[p][c * 4 + 2]; u.w = pk[p][c * 4 + 3];
            dst[c] = u;
        }
    }
    atomicAdd(&cs[0 * DD + o], xs1);  atomicAdd(&cs[1 * DD + o], xs2);  atomicAdd(&cs[2 * DD + o], xs3);
    atomicAdd(&cs[3 * DD + o], ss1);  atomicAdd(&cs[4 * DD + o], ss2);  atomicAdd(&cs[5 * DD + o], ss3);
    atomicAdd(&cs[6 * DD + o], ys1);  atomicAdd(&cs[7 * DD + o], ys2);  atomicAdd(&cs[8 * DD + o], ys3);
    atomicAdd(&cs[9 * DD + o], sy1);  atomicAdd(&cs[10 * DD + o], s2y); atomicAdd(&cs[11 * DD + o], sy2);
}

__global__ __launch_bounds__(256) void gemm3_kernel(
    const unsigned short* __restrict__ pl, const float* __restrict__ w,
    float* __restrict__ out)
{
    __shared__ unsigned short ldsA[128 * 32];
    __shared__ unsigned short ldsB[128 * 32];
    const int t    = threadIdx.x;
    const int lane = t & 63;
    const int wid  = t >> 6;
    const int g     = blockIdx.z;
    const int tileI = blockIdx.x & 3;
    const int tileO = blockIdx.x >> 2;
    const int kt0   = blockIdx.y * 16;
    const int aplane = (g == 0) ? 0 : (g == 1) ? 1 : 2;
    const int bplane = (g == 1) ? 4 : 3;
    const unsigned short* Ap = pl + (size_t)aplane * PLANE;
    const unsigned short* Bp = pl + (size_t)bplane * PLANE;
    const int wo = (wid >> 1) * 64;
    const int wi = (wid & 1) * 64;
    const int l15 = lane & 15;
    const int kchunk = (lane >> 4) * 8;
    f32x4 acc[4][4];
#pragma unroll
    for (int m = 0; m < 4; ++m)
#pragma unroll
        for (int n = 0; n < 4; ++n) acc[m][n] = (f32x4)0.f;
    unsigned short* ldsAw = ldsA + wid * 512;
    unsigned short* ldsBw = ldsB + wid * 512;
    const size_t tg = (size_t)t * 8;
    for (int kt = 0; kt < 16; ++kt) {
        const size_t abase = ((size_t)(kt0 + kt) * DD + tileO * 128) * 32;
        const size_t bbase = ((size_t)(kt0 + kt) * DD + tileI * 128) * 32;
        __syncthreads();
        gload_lds16(Ap + abase + tg,        ldsAw);
        gload_lds16(Ap + abase + 2048 + tg, ldsAw + 2048);
        gload_lds16(Bp + bbase + tg,        ldsBw);
        gload_lds16(Bp + bbase + 2048 + tg, ldsBw + 2048);
        __syncthreads();
        short8 af[4], bf[4];
#pragma unroll
        for (int m = 0; m < 4; ++m)
            af[m] = *(const short8*)&ldsA[(wo + m * 16 + l15) * 32 + kchunk];
#pragma unroll
        for (int n = 0; n < 4; ++n)
            bf[n] = *(const short8*)&ldsB[(wi + n * 16 + l15) * 32 + kchunk];
#pragma unroll
        for (int m = 0; m < 4; ++m)
#pragma unroll
            for (int n = 0; n < 4; ++n)
                acc[m][n] = __builtin_amdgcn_mfma_f32_16x16x32_bf16(af[m], bf[n], acc[m][n], 0, 0, 0);
    }
    const float invB = 1.0f / (float)BD;
    const int l4 = lane >> 4;
#pragma unroll
    for (int m = 0; m < 4; ++m) {
#pragma unroll
        for (int n = 0; n < 4; ++n) {
#pragma unroll
            for (int r = 0; r < 4; ++r) {
                const int o = tileO * 128 + wo + m * 16 + l4 * 4 + r;
                const int i = tileI * 128 + wi + n * 16 + l15;
                float v = acc[m][n][r] * invB;
                if (g == 2) v *= w[o * DD + i];
                atomicAdd(&out[o * DD + i], v);
            }
        }
    }
}

__global__ __launch_bounds__(256) void rank1_kernel(
    const float* __restrict__ w, const float* __restrict__ pw,
    const float* __restrict__ cs, float* __restrict__ out)
{
    const int idx = blockIdx.x * 256 + threadIdx.x;
    const int o = idx >> 9;
    const int i = idx & 511;
    const float wv = w[idx];
    const float w2 = wv * wv, w3 = w2 * wv;
    const float invB = 1.0f / (float)BD;
    float acc = (float)BD * (pw[0] + pw[1] * wv + pw[2] * w2 + pw[3] * w3);
    acc += cs[0 * DD + i] * polyev2(pw[20], pw[21], pw[22], wv, w2);
    acc += cs[1 * DD + i] * (pw[30] + pw[31] * wv);
    acc += cs[2 * DD + i] * pw[34];
    acc += cs[6 * DD + o]  * polyev2(pw[4],  pw[5],  pw[6],  wv, w2);
    acc += cs[7 * DD + o]  * (pw[7] + pw[8] * wv);
    acc += cs[8 * DD + o]  * pw[9];
    acc += cs[3 * DD + o]  * polyev2(pw[10], pw[11], pw[12], wv, w2);
    acc += cs[9 * DD + o]  * (pw[13] + pw[14] * wv);
    acc += cs[11 * DD + o] * pw[15];
    acc += cs[4 * DD + o]  * (pw[16] + pw[17] * wv);
    acc += cs[10 * DD + o] * pw[18];
    acc += cs[5 * DD + o]  * pw[19];
    out[idx] += invB * acc;
}

extern "C" void kernel_launch(void* const* d_in, const int* in_sizes, int n_in,
                              void* d_out, int out_size, void* d_ws, size_t ws_size,
                              hipStream_t stream) {
    const float* x  = (const float*)d_in[0];
    const float* s  = (const float*)d_in[1];
    const float* y  = (const float*)d_in[2];
    const float* w  = (const float*)d_in[3];
    const float* b  = (const float*)d_in[4];
    const float* pw = (const float*)d_in[5];
    const float* pb = (const float*)d_in[6];
    float* out = (float*)d_out;

    const size_t planeBytes = (size_t)PLANE * 2 * NPLANES;            // 41.9 MB
    const size_t partBytes  = (size_t)KSPLIT * NELEM * sizeof(float); // 33.6 MB
    const size_t cspBytes   = (size_t)1024 * 12 * 64 * sizeof(float); //  3.1 MB
    const size_t csBytes    = 12 * DD * sizeof(float);

    if (ws_size >= planeBytes + partBytes + cspBytes + csBytes) {
        unsigned short* pl = (unsigned short*)d_ws;
        float* part = (float*)((char*)d_ws + planeBytes);
        float* csp  = (float*)((char*)d_ws + planeBytes + partBytes);
        float* cs   = (float*)((char*)d_ws + planeBytes + partBytes + cspBytes);
        prep3_kernel<<<dim3(8, 128), 256, 0, stream>>>(x, s, y, pw, pl, csp);
        reduce_cs_kernel<<<24, 256, 0, stream>>>(csp, cs);
        gemm_kernel<<<512, 256, 0, stream>>>(pl, w, part);
        reduce_rank1_kernel<<<1024, 256, 0, stream>>>(part, w, pw, cs, out);
        deltab_kernel<<<2, 256, 0, stream>>>(b, pb, cs, out);
    } else {
        unsigned short* pl = (unsigned short*)d_ws;
        float* cs = (float*)((char*)d_ws + planeBytes);
        hipMemsetAsync(cs, 0, csBytes, stream);
        hipMemsetAsync(out, 0, (size_t)out_size * sizeof(float), stream);
        prep_old_kernel<<<dim3(8, 64), 256, 0, stream>>>(x, s, y, pw, pl, cs);
        gemm3_kernel<<<dim3(16, 16, 3), 256, 0, stream>>>(pl, w, out);
        rank1_kernel<<<dim3((DD * DD) / 256), 256, 0, stream>>>(w, pw, cs, out);
        deltab_kernel<<<2, 256, 0, stream>>>(b, pb, cs, out);
    }
}